// Round 2
// baseline (468.362 us; speedup 1.0000x reference)
//
#include <hip/hip_runtime.h>

// GR4J daily hydrological model, round 8: consumer stripped to the bare
// r-chain; conv + input handling rebalanced onto the producer.
// T=4015 steps, WARMUP=365, B=2048 basins.
//
// R7 (async gl_lds input staging) gained 359->332 us at the dispatch level
// -- real but small: load latency was a minor term. The consumer wave is
// the wall (~199 cyc/step, unchanged R5->R7). Its step is a CYCLIC chain
// with three chained transcendentals (sqrt(rx) -> gex -> r2 -> r2^4 ->
// sqrt -> rsq -> rn): chain ~= 3*T_trans + 28 cyc, plus ~80 issue-cyc of
// conv/LDS/store work sharing the same instruction stream.
//
// R8 changes:
//  - conv (q9,q1) moves to the PRODUCER: pr stays in producer registers,
//    UH history lives there; producer writes packed float2 (q9,q1) per
//    step (ds_write_b64). Consumer = ds_read_b64 + routing chain + store.
//  - producer rcp removed from the s-chain: rpe = 1/(dp*de) with
//    dp*de in [1,1.0202) -> cubic series 1-u+u^2-u^3, err <= u^4 < 1.7e-7
//    (same order as v_rcp's own error).
//  - warmup conv-reset (t=365) moves to the producer: chunk c=33 holds
//    t=363..373, reset history before i==2 (uniform predicated, 1/365).
//    Consumer k=6 special case keeps only the dump->real store switch.
//  - flag protocol, inbuf staging ring, counted vmcnt(22): unchanged.
//
// Where the new dur lands measures T_trans and decides whether R9 attacks
// the two chained root-ops numerically (poly + Newton for (1+z)^-1/4).
//
// Warmup without per-step predication: stores for t<365 go to out rows [t]
// (t<=364), later overwritten by the real rows (same wave, same address,
// program-ordered).
//
// Approximations (threshold 3.97e-2; measured absmax with these: 7.8e-3):
//  - tanh(x) ~= x for x<=0.01; (1+z)^(-1/4) 3-term series in prod (z<=.039);
//  - rpe = 1/(dp*de) cubic series (u<=0.0202, err<=1.7e-7);
//  - routing keeps exact-form v_sqrt/v_rsq.

#define T_TOTAL 4015
#define NWARM   365
#define NB      2048
#define BSTEP   55
#define NBATCH  73          // 73 * 55 = 4015
#define CH      11          // producer staging chunk: 11 steps
#define NCHUNK  365         // 365 * 11 = 4015

typedef __attribute__((address_space(3))) float       lds_f;
typedef __attribute__((address_space(1))) const float glb_f;

__device__ __forceinline__ void gl_lds_dword(const float* g, float* l) {
    // async global->LDS, 4B per lane; LDS dst = uniform base + lane*4
    __builtin_amdgcn_global_load_lds((glb_f*)(uintptr_t)g,
                                     (lds_f*)(uintptr_t)l, 4, 0, 0);
}

__global__ __launch_bounds__(128, 1)
void gr4j_kernel(const float2* __restrict__ pe_in,   // [T_TOTAL*NB] (p,e)
                 const float*  __restrict__ params,  // [NB,4]
                 float*        __restrict__ out)     // [(T_TOTAL-NWARM)*NB]
{
    const int lane = threadIdx.x & 63;
    const int wid  = threadIdx.x >> 6;
    const int b    = blockIdx.x * 64 + lane;

    __shared__ float2 qbuf[2][BSTEP * 64];           // 56.3 KB (q9,q1) dbuf
    __shared__ float  inbuf[4][CH][2][64];           // 11.3 KB input ring
    __shared__ int produced;                         // batches written by w0
    __shared__ int consumed;                         // batches read by w1
    if (threadIdx.x == 0) { produced = 0; consumed = 0; }
    __syncthreads();   // the only barrier: flag init (outside the pipeline)

    const float x1 = 100.0f + params[b * 4 + 0] * 1100.0f;
    const float x2 = -5.0f  + params[b * 4 + 1] * 8.0f;
    const float x3 = 20.0f  + params[b * 4 + 2] * 280.0f;
    const float x4 = 1.1f   + params[b * 4 + 3] * 1.8f;
    const float invx1 = __builtin_amdgcn_rcpf(x1);
    const float invx3 = __builtin_amdgcn_rcpf(x3);
    const float c49   = (4.0f / 9.0f) * invx1;
    const float c49_2 = c49 * c49;
    const float c4s   = c49_2 * c49_2;               // ((4/9)/x1)^4
    const float i3_2  = invx3 * invx3;
    const float c4r   = i3_2 * i3_2;                 // (1/x3)^4

    if (wid == 0) {
        // ========= producer: s-chain -> pr -> conv -> (q9,q1) =========
        // UH ordinates (once; precise powf fine here).
        float u10, u11, u12, u20, u21, u22, u23, u24, u25;
        {
            float sh[3];
            #pragma unroll
            for (int j = 1; j <= 3; ++j)
                sh[j - 1] = powf(fminf((float)j / x4, 1.0f), 2.5f);
            u10 = sh[0]; u11 = sh[1] - sh[0]; u12 = sh[2] - sh[1];
            float s2h[6];
            #pragma unroll
            for (int j = 1; j <= 6; ++j) {
                float rr = (float)j / x4;
                s2h[j - 1] = ((float)j <= x4) ? 0.5f * powf(rr, 2.5f)
                           : 1.0f - 0.5f * powf(fmaxf(2.0f - rr, 0.0f), 2.5f);
            }
            u20 = s2h[0];          u21 = s2h[1] - s2h[0]; u22 = s2h[2] - s2h[1];
            u23 = s2h[3] - s2h[2]; u24 = s2h[4] - s2h[3]; u25 = s2h[5] - s2h[4];
        }

        float s = 0.5f * x1;
        float ph0 = 0.f, ph1 = 0.f, ph2 = 0.f, ph3 = 0.f, ph4 = 0.f;

        auto prod_step = [&](float p_, float e_) -> float {
            const float diff = p_ - e_;
            const float pn = fmaxf(diff, 0.0f);
            const float en = fmaxf(-diff, 0.0f);
            const float ap = pn * invx1;             // ~= tanh(pn/x1)
            const float ae = en * invx1;             // ~= tanh(en/x1)
            const float sx = s * invx1;
            const float dp = fmaf(sx, ap, 1.0f);
            const float de = fmaf(1.0f - sx, ae, 1.0f);
            const float n1 = fmaf(-sx, sx, 1.0f);
            const float nump = pn * n1;              // x1*(1-sx^2)*(pn/x1)
            const float nume = (sx * en) * (2.0f - sx);
            // rpe = 1/(dp*de), dp*de in [1,1.0202): cubic series, err<=u^4
            const float u  = fmaf(dp, de, -1.0f);
            const float t1 = 1.0f - u;
            const float t2 = fmaf(-u, t1, 1.0f);
            const float rpe = fmaf(-u, t2, 1.0f);    // 1-u+u^2-u^3
            const float a_ = nump * de;
            const float b_ = nume * dp;
            const float s2 = fmaf(a_ - b_, rpe, s);  // s - es + ps
            const float ps = a_ * rpe;
            const float s22 = s2 * s2;
            const float s24 = s22 * s22;
            const float z = c4s * s24;               // <= 0.039
            float w = fmaf(z, 15.0f / 128.0f, -5.0f / 32.0f);
            w = fmaf(z, w, 0.25f);
            const float perc = (s2 * z) * w;         // s2*(1-(1+z)^-.25)
            s = s2 - perc;
            return perc + (pn - ps);
        };

        // per-lane float base: element (t*NB+b) float2 == float idx 2*(t*NB+b)
        const float* pbase = (const float*)pe_in + 2 * b;

        // prologue: stage chunks 0,1 (44 dword ops in flight)
        #pragma unroll
        for (int cc = 0; cc < 2; ++cc) {
            const float* cb = pbase + (size_t)cc * CH * 2 * NB;
            #pragma unroll
            for (int i = 0; i < CH; ++i) {
                gl_lds_dword(cb + (size_t)i * 2 * NB,     &inbuf[cc][i][0][0]);
                gl_lds_dword(cb + (size_t)i * 2 * NB + 1, &inbuf[cc][i][1][0]);
            }
        }

        for (int c = 0; c < NCHUNK; ++c) {
            const int k  = c / 5;                    // batch index
            const int ph = c - 5 * k;                // chunk within batch
            if (ph == 0 && k >= 2) {
                while (__hip_atomic_load(&consumed, __ATOMIC_ACQUIRE,
                                         __HIP_MEMORY_SCOPE_WORKGROUP) < k - 1) {}
            }

            // Counted wait: newest 22 ops (chunk c+1) may remain in flight;
            // all older ops (chunk c) are retired => slot c&3 is resident.
            if (c < NCHUNK - 1) asm volatile("s_waitcnt vmcnt(22)" ::: "memory");
            else                asm volatile("s_waitcnt vmcnt(0)"  ::: "memory");

            // burst-read the chunk's 11 (p,e) pairs LDS->regs
            const int slot = c & 3;
            float pf_p[CH], pf_e[CH];
            #pragma unroll
            for (int i = 0; i < CH; ++i) {
                pf_p[i] = inbuf[slot][i][0][lane];
                pf_e[i] = inbuf[slot][i][1][lane];
            }

            // issue chunk c+2 while the ds_reads above are in flight
            if (c + 2 < NCHUNK) {
                const float* cb = pbase + (size_t)(c + 2) * CH * 2 * NB;
                const int s2i = (c + 2) & 3;         // != slot (differ by 2 mod 4)
                #pragma unroll
                for (int i = 0; i < CH; ++i) {
                    gl_lds_dword(cb + (size_t)i * 2 * NB,     &inbuf[s2i][i][0][0]);
                    gl_lds_dword(cb + (size_t)i * 2 * NB + 1, &inbuf[s2i][i][1][0]);
                }
            }

            // 11 steps: s-chain -> pr -> conv -> packed (q9,q1) to LDS.
            // Chunk c covers t = 11c..11c+10. c==33 holds t=365 at i==2:
            // reference restarts conv history at WARMUP (s,r carry over,
            // conv history does not) -> zero history before that step.
            float2* dst = &qbuf[k & 1][(ph * CH) * 64 + lane];
            const bool rst = (c == 33);
            #pragma unroll
            for (int i = 0; i < CH; ++i) {
                const float pr = prod_step(pf_p[i], pf_e[i]);
                if (i == 2 && rst) { ph0 = ph1 = ph2 = ph3 = ph4 = 0.0f; }
                const float q9 = fmaf(u10, pr, fmaf(u11, ph0, u12 * ph1));
                const float q1 = fmaf(u20, pr, fmaf(u21, ph0, fmaf(u22, ph1,
                                 fmaf(u23, ph2, fmaf(u24, ph3, u25 * ph4)))));
                ph4 = ph3; ph3 = ph2; ph2 = ph1; ph1 = ph0; ph0 = pr;
                dst[i * 64] = make_float2(q9, q1);
            }

            if (ph == 4)
                __hip_atomic_store(&produced, k + 1, __ATOMIC_RELEASE,
                                   __HIP_MEMORY_SCOPE_WORKGROUP);
        }
    } else {
        // ========= consumer: routing chain + store, nothing else =========
        float r = 0.5f * x3;

        auto w1_step = [&](float2 qin) -> float {
            const float rq = r + qin.x;              // off the gex path
            const float rx = r * invx3;
            const float srx = __builtin_amdgcn_sqrtf(rx);
            const float gex = (x2 * ((rx * rx) * rx)) * srx; // x2*(r/x3)^3.5
            const float r2 = fmaxf(0.0f, rq + gex);
            const float r22 = r2 * r2;
            const float r24 = r22 * r22;
            const float v4p1 = fmaf(c4r, r24, 1.0f);
            const float rn = r2 * __builtin_amdgcn_rsqf(__builtin_amdgcn_sqrtf(v4p1));
            const float qr = r2 - rn;
            r = rn;
            return qr + fmaxf(0.0f, qin.y + gex);
        };

        for (int k = 0; k < NBATCH; ++k) {
            while (__hip_atomic_load(&produced, __ATOMIC_ACQUIRE,
                                     __HIP_MEMORY_SCOPE_WORKGROUP) < k + 1) {}
            const float2* src = &qbuf[k & 1][0] + lane;
            if (k != 6) {
                // k<6: t=55k..55k+54 <= 329 -> dump rows [t] (overwritten by
                // t'=365+row later, same wave => ordered). k>=7: rows t-365.
                float* ob = (k < 6)
                    ? out + (size_t)(k * BSTEP) * NB + b
                    : out + (size_t)(k * BSTEP - NWARM) * NB + b;
                float2 qq[11];
                #pragma unroll
                for (int i = 0; i < 11; ++i) qq[i] = src[i * 64];
                for (int g = 0; g < 5; ++g) {
                    const float2* sp = src + (g + 1) * (11 * 64);
                    float* ob2 = ob + (size_t)(g * 11) * NB;
                    if (g < 4) {
                        #pragma unroll
                        for (int i = 0; i < 11; ++i) {
                            const float2 qv = qq[i];
                            qq[i] = sp[i * 64];          // prefetch 11 ahead
                            ob2[(size_t)i * NB] = w1_step(qv);
                        }
                    } else {
                        #pragma unroll
                        for (int i = 0; i < 11; ++i)
                            ob2[(size_t)i * NB] = w1_step(qq[i]);
                    }
                }
            } else {
                // Special batch k=6: t=330..384. Store base switches
                // dump->real at j==35 (t==365). Conv history reset now
                // happens in the producer. Fully unrolled: folds at compile
                // time.
                float* dumpb = out + (size_t)330 * NB + b;   // rows 330..364
                float* realb = out + b;                      // rows 0..19
                float2 qq[11];
                #pragma unroll
                for (int i = 0; i < 11; ++i) qq[i] = src[i * 64];
                #pragma unroll
                for (int g = 0; g < 5; ++g) {
                    #pragma unroll
                    for (int i = 0; i < 11; ++i) {
                        const int j = g * 11 + i;            // step in batch
                        const float2 qv = qq[i];
                        if (g < 4) qq[i] = src[(j + 11) * 64];
                        const float q = w1_step(qv);
                        if (j < 35) dumpb[(size_t)j * NB] = q;
                        else        realb[(size_t)(j - 35) * NB] = q;
                    }
                }
            }
            __hip_atomic_store(&consumed, k + 1, __ATOMIC_RELEASE,
                               __HIP_MEMORY_SCOPE_WORKGROUP);
        }
    }
}

extern "C" void kernel_launch(void* const* d_in, const int* in_sizes, int n_in,
                              void* d_out, int out_size, void* d_ws, size_t ws_size,
                              hipStream_t stream) {
    const float2* pe_in  = (const float2*)d_in[0];   // p_and_e [4015,2048,2]
    const float*  params = (const float*)d_in[1];    // parameters [2048,4]
    float* out = (float*)d_out;                      // [3650,2048,1]
    (void)in_sizes; (void)n_in; (void)out_size; (void)d_ws; (void)ws_size;

    gr4j_kernel<<<dim3(NB / 64), dim3(128), 0, stream>>>(pe_in, params, out);
}

// Round 3
// 369.945 us; speedup vs baseline: 1.2660x; 1.2660x over previous
//
#include <hip/hip_runtime.h>

// GR4J daily hydrological model, round 9: 4-stage / 4-wave pipeline.
// T=4015 steps, WARMUP=365, B=2048 basins, 32 blocks x 256 threads.
//
// R8 (conv moved into producer) REGRESSED 332->392: wall tracks the
// heaviest wave ~1:1 (fit: wall ~= 1.3*heaviest_issue + 95). So R9 strips
// both serial chains bare and gives every parallelizable job its own wave
// (2 SIMDs/CU were idle):
//   w0: input staging only. global_load_lds size=16, 32 active lanes
//       (16B/lane = whole 128-float (p,e) row per step), 11 ops/chunk,
//       counted s_waitcnt vmcnt(11), relaxed flags. No other vmem ever ->
//       clean vmcnt bookkeeping.
//   w1: s-chain only. ds_read_b64 (p,e) x11 batched, 11 prod_steps
//       (arithmetic bit-identical to R8), pr -> LDS ring.
//   w2: conv only. pr -> 9-tap UH conv -> packed float2 (q9,q1) -> ring.
//       Conv-history reset at t=365 (chunk 33, i==2) lives here.
//   w3: r-chain + store. ds_read_b64 (q9,q1), routing chain (bit-identical),
//       fire-and-forget global stores.
// Flag discipline (lesson from R6-R8): RELEASE stores in waves with vmem
// in flight compile to s_waitcnt vmcnt(0) -> silent pipeline drains. Here:
//   w1/w2 flags: st RELEASE (those waves have zero vmem -> free).
//   w0/w3 flags: RELAXED + explicit asm s_waitcnt (vmcnt counted / lgkmcnt).
// Dump/real WAW ordering (warmup rows rewritten later by the same wave):
// two one-time vmcnt(0) in w3 at chunks 33 and 34 cover all overlaps.
//
// Rings: 4 chunks deep, chunk = 11 steps, chunk-granular flags with
// explicit backpressure counters (producer of ring slot c&3 waits for its
// consumer to have finished chunk c-4).
//
// Approximations (threshold 3.97e-2; measured absmax: 7.8e-3, bit-stable
// since R7 -- any change here means a staging bug, not a numerics change):
//  - tanh(x) ~= x for x<=0.01; (1+z)^(-1/4) 3-term series in prod;
//  - rpe = 1/(dp*de) cubic series (u<=0.0202, err<=1.7e-7);
//  - routing keeps exact-form v_sqrt/v_rsq.

#define T_TOTAL 4015
#define NWARM   365
#define NB      2048
#define CH      11          // pipeline chunk: 11 steps
#define NCHUNK  365         // 365 * 11 = 4015

typedef __attribute__((address_space(3))) float       lds_f;
typedef __attribute__((address_space(1))) const float glb_f;

__device__ __forceinline__ void gl_lds_16(const float* g, float* l) {
    // async global->LDS, 16B per active lane; LDS dst = uniform base + lane*16
    __builtin_amdgcn_global_load_lds((glb_f*)(uintptr_t)g,
                                     (lds_f*)(uintptr_t)l, 16, 0, 0);
}

__device__ __forceinline__ int ld_acq(int* p) {
    return __hip_atomic_load(p, __ATOMIC_ACQUIRE, __HIP_MEMORY_SCOPE_WORKGROUP);
}
__device__ __forceinline__ void st_rel(int* p, int v) {
    __hip_atomic_store(p, v, __ATOMIC_RELEASE, __HIP_MEMORY_SCOPE_WORKGROUP);
}
__device__ __forceinline__ void st_rlx(int* p, int v) {
    __hip_atomic_store(p, v, __ATOMIC_RELAXED, __HIP_MEMORY_SCOPE_WORKGROUP);
}

__global__ __launch_bounds__(256, 1)
void gr4j_kernel(const float2* __restrict__ pe_in,   // [T_TOTAL*NB] (p,e)
                 const float*  __restrict__ params,  // [NB,4]
                 float*        __restrict__ out)     // [(T_TOTAL-NWARM)*NB]
{
    const int lane = threadIdx.x & 63;
    const int wid  = threadIdx.x >> 6;
    const int b    = blockIdx.x * 64 + lane;

    __shared__ float4 inbuf[4][CH][32];              // 22.5 KB input ring
    __shared__ float  prring[4][CH * 64];            // 11.3 KB pr ring
    __shared__ float2 qring[4][CH * 64];             // 22.5 KB (q9,q1) ring
    __shared__ int in_ready;                         // chunks LDS-resident
    __shared__ int w1_done;                          // chunks s-chain done
    __shared__ int w2_done;                          // chunks conv done
    __shared__ int w3_done;                          // chunks routed/stored
    if (threadIdx.x == 0) { in_ready = 0; w1_done = 0; w2_done = 0; w3_done = 0; }
    __syncthreads();   // the only barrier: flag init (outside the pipeline)

    if (wid == 0) {
        // =============== w0: input staging, nothing else ===============
        // chunk c, step i: row t=11c+i. 32 lanes x float4 = 128 floats =
        // the block's 64 (p,e) pairs. Global float4 idx = t*1024+bx*32+lane.
        const float4* p4 = (const float4*)pe_in + (size_t)blockIdx.x * 32 + lane;
        const bool active = (lane < 32);

        // prologue: stage chunks 0,1 (22 ops in flight)
        if (active) {
            #pragma unroll
            for (int cc = 0; cc < 2; ++cc)
                #pragma unroll
                for (int i = 0; i < CH; ++i)
                    gl_lds_16((const float*)(p4 + (size_t)(cc * CH + i) * 1024),
                              (float*)&inbuf[cc][i][0]);
        }

        for (int c = 0; c <= NCHUNK - 3; ++c) {
            // slot (c+2)&3 reuse: w1 must be done with chunk c-2
            if (c >= 2) while (ld_acq(&w1_done) < c - 1) {}
            if (active) {
                const int slot = (c + 2) & 3;
                const float4* cb = p4 + (size_t)(c + 2) * CH * 1024;
                #pragma unroll
                for (int i = 0; i < CH; ++i)
                    gl_lds_16((const float*)(cb + (size_t)i * 1024),
                              (float*)&inbuf[slot][i][0]);
            }
            // newest chunk (c+2, 11 ops) may stay in flight; chunks <= c+1
            // are LDS-resident once vmcnt <= 11.
            asm volatile("s_waitcnt vmcnt(11)" ::: "memory");
            if (lane == 0) st_rlx(&in_ready, c + 2);
        }
        asm volatile("s_waitcnt vmcnt(0)" ::: "memory");
        if (lane == 0) st_rlx(&in_ready, NCHUNK);
    } else if (wid == 1) {
        // ================== w1: s-chain -> pr ==================
        const float x1 = 100.0f + params[b * 4 + 0] * 1100.0f;
        const float invx1 = __builtin_amdgcn_rcpf(x1);
        const float c49   = (4.0f / 9.0f) * invx1;
        const float c49_2 = c49 * c49;
        const float c4s   = c49_2 * c49_2;           // ((4/9)/x1)^4
        float s = 0.5f * x1;

        auto prod_step = [&](float p_, float e_) -> float {
            const float diff = p_ - e_;
            const float pn = fmaxf(diff, 0.0f);
            const float en = fmaxf(-diff, 0.0f);
            const float ap = pn * invx1;             // ~= tanh(pn/x1)
            const float ae = en * invx1;             // ~= tanh(en/x1)
            const float sx = s * invx1;
            const float dp = fmaf(sx, ap, 1.0f);
            const float de = fmaf(1.0f - sx, ae, 1.0f);
            const float n1 = fmaf(-sx, sx, 1.0f);
            const float nump = pn * n1;              // x1*(1-sx^2)*(pn/x1)
            const float nume = (sx * en) * (2.0f - sx);
            // rpe = 1/(dp*de), dp*de in [1,1.0202): cubic series, err<=u^4
            const float u  = fmaf(dp, de, -1.0f);
            const float t1 = 1.0f - u;
            const float t2 = fmaf(-u, t1, 1.0f);
            const float rpe = fmaf(-u, t2, 1.0f);    // 1-u+u^2-u^3
            const float a_ = nump * de;
            const float b_ = nume * dp;
            const float s2 = fmaf(a_ - b_, rpe, s);  // s - es + ps
            const float ps = a_ * rpe;
            const float s22 = s2 * s2;
            const float s24 = s22 * s22;
            const float z = c4s * s24;               // <= 0.039
            float w = fmaf(z, 15.0f / 128.0f, -5.0f / 32.0f);
            w = fmaf(z, w, 0.25f);
            const float perc = (s2 * z) * w;         // s2*(1-(1+z)^-.25)
            s = s2 - perc;
            return perc + (pn - ps);
        };

        for (int c = 0; c < NCHUNK; ++c) {
            while (ld_acq(&in_ready) < c + 1) {}
            if (c >= 4) while (ld_acq(&w2_done) < c - 3) {}
            const int slot = c & 3;
            // lane's (p,e) = float2 idx i*64+lane of the chunk's rows
            const float2* ib = (const float2*)&inbuf[slot][0][0];
            float2 pe[CH];
            #pragma unroll
            for (int i = 0; i < CH; ++i) pe[i] = ib[i * 64 + lane];
            float* dst = &prring[slot][lane];
            #pragma unroll
            for (int i = 0; i < CH; ++i)
                dst[i * 64] = prod_step(pe[i].x, pe[i].y);
            if (lane == 0) st_rel(&w1_done, c + 1);  // no vmem in w1: free
        }
    } else if (wid == 2) {
        // ================== w2: conv -> (q9,q1) ==================
        const float x4 = 1.1f + params[b * 4 + 3] * 1.8f;
        float u10, u11, u12, u20, u21, u22, u23, u24, u25;
        {
            float sh[3];
            #pragma unroll
            for (int j = 1; j <= 3; ++j)
                sh[j - 1] = powf(fminf((float)j / x4, 1.0f), 2.5f);
            u10 = sh[0]; u11 = sh[1] - sh[0]; u12 = sh[2] - sh[1];
            float s2h[6];
            #pragma unroll
            for (int j = 1; j <= 6; ++j) {
                float rr = (float)j / x4;
                s2h[j - 1] = ((float)j <= x4) ? 0.5f * powf(rr, 2.5f)
                           : 1.0f - 0.5f * powf(fmaxf(2.0f - rr, 0.0f), 2.5f);
            }
            u20 = s2h[0];          u21 = s2h[1] - s2h[0]; u22 = s2h[2] - s2h[1];
            u23 = s2h[3] - s2h[2]; u24 = s2h[4] - s2h[3]; u25 = s2h[5] - s2h[4];
        }
        float ph0 = 0.f, ph1 = 0.f, ph2 = 0.f, ph3 = 0.f, ph4 = 0.f;

        auto conv_step = [&](float pr) -> float2 {
            const float q9 = fmaf(u10, pr, fmaf(u11, ph0, u12 * ph1));
            const float q1 = fmaf(u20, pr, fmaf(u21, ph0, fmaf(u22, ph1,
                             fmaf(u23, ph2, fmaf(u24, ph3, u25 * ph4)))));
            ph4 = ph3; ph3 = ph2; ph2 = ph1; ph1 = ph0; ph0 = pr;
            return make_float2(q9, q1);
        };

        for (int c = 0; c < NCHUNK; ++c) {
            while (ld_acq(&w1_done) < c + 1) {}
            if (c >= 4) while (ld_acq(&w3_done) < c - 3) {}
            const int slot = c & 3;
            const float* src = &prring[slot][lane];
            float prr[CH];
            #pragma unroll
            for (int i = 0; i < CH; ++i) prr[i] = src[i * 64];
            float2* dst = &qring[slot][lane];
            if (c != 33) {
                #pragma unroll
                for (int i = 0; i < CH; ++i) dst[i * 64] = conv_step(prr[i]);
            } else {
                // chunk 33: t=363..373; reference restarts conv history at
                // t=365 (i==2). s,r carry over; conv history does not.
                #pragma unroll
                for (int i = 0; i < CH; ++i) {
                    if (i == 2) { ph0 = ph1 = ph2 = ph3 = ph4 = 0.0f; }
                    dst[i * 64] = conv_step(prr[i]);
                }
            }
            if (lane == 0) st_rel(&w2_done, c + 1);  // no vmem in w2: free
        }
    } else {
        // ================== w3: r-chain + store ==================
        const float x2 = -5.0f + params[b * 4 + 1] * 8.0f;
        const float x3 = 20.0f + params[b * 4 + 2] * 280.0f;
        const float invx3 = __builtin_amdgcn_rcpf(x3);
        const float i3_2  = invx3 * invx3;
        const float c4r   = i3_2 * i3_2;             // (1/x3)^4
        float r = 0.5f * x3;

        auto w3_step = [&](float2 qin) -> float {
            const float rq = r + qin.x;              // off the gex path
            const float rx = r * invx3;
            const float srx = __builtin_amdgcn_sqrtf(rx);
            const float gex = (x2 * ((rx * rx) * rx)) * srx; // x2*(r/x3)^3.5
            const float r2 = fmaxf(0.0f, rq + gex);
            const float r22 = r2 * r2;
            const float r24 = r22 * r22;
            const float v4p1 = fmaf(c4r, r24, 1.0f);
            const float rn = r2 * __builtin_amdgcn_rsqf(__builtin_amdgcn_sqrtf(v4p1));
            const float qr = r2 - rn;
            r = rn;
            return qr + fmaxf(0.0f, qin.y + gex);
        };

        for (int c = 0; c < NCHUNK; ++c) {
            while (ld_acq(&w2_done) < c + 1) {}
            // Dump/real WAW ordering, one-time waits:
            //  c==33: dumps rows<=362 (chunks<=32) retired before real rows
            //         0..8 are issued this chunk.
            //  c==34: dumps 363,364 (chunk 33) retired before their real
            //         twins (chunk 66) are issued later in program order.
            if (c == 33 || c == 34)
                asm volatile("s_waitcnt vmcnt(0)" ::: "memory");
            const int slot = c & 3;
            const float2* src = &qring[slot][lane];
            float2 qq[CH];
            #pragma unroll
            for (int i = 0; i < CH; ++i) qq[i] = src[i * 64];
            if (c != 33) {
                // c<33: t=11c+i<=362 -> dump rows [t] (rewritten by
                // t'=365+row later, same wave, ordered by c==34 wait).
                // c>=34: rows t-365.
                float* ob = out + (size_t)((c < 33) ? 11 * c
                                                    : 11 * c - NWARM) * NB + b;
                #pragma unroll
                for (int i = 0; i < CH; ++i)
                    ob[(size_t)i * NB] = w3_step(qq[i]);
            } else {
                // chunk 33: i=0,1 -> dump rows 363,364; i>=2 -> real rows 0..8
                float* dumpb = out + (size_t)363 * NB + b;
                float* realb = out + b;
                #pragma unroll
                for (int i = 0; i < CH; ++i) {
                    const float q = w3_step(qq[i]);
                    if (i < 2) dumpb[(size_t)i * NB] = q;
                    else       realb[(size_t)(i - 2) * NB] = q;
                }
            }
            // qring reads retired (results consumed); flag must not drain
            // the global stores -> RELAXED + lgkmcnt only.
            asm volatile("s_waitcnt lgkmcnt(0)" ::: "memory");
            if (lane == 0) st_rlx(&w3_done, c + 1);
        }
    }
}

extern "C" void kernel_launch(void* const* d_in, const int* in_sizes, int n_in,
                              void* d_out, int out_size, void* d_ws, size_t ws_size,
                              hipStream_t stream) {
    const float2* pe_in  = (const float2*)d_in[0];   // p_and_e [4015,2048,2]
    const float*  params = (const float*)d_in[1];    // parameters [2048,4]
    float* out = (float*)d_out;                      // [3650,2048,1]
    (void)in_sizes; (void)n_in; (void)out_size; (void)d_ws; (void)ws_size;

    gr4j_kernel<<<dim3(NB / 64), dim3(256), 0, stream>>>(pe_in, params, out);
}